// Round 2
// baseline (25611.383 us; speedup 1.0000x reference)
//
#include <hip/hip_runtime.h>
#include <hip/hip_bf16.h>

// Problem dims (fixed by reference)
#define BATCH 1024
#define DLAT  512
#define HHID  1024
#define TPTS  64
#define BD    (BATCH * DLAT)   // 524288
#define BH    (BATCH * HHID)   // 1048576

// GEMM tile config: 64x64 tile, BK=16, 256 threads, 4x4 per thread
#define BM 64
#define BN 64
#define BK 16

using bf16 = __hip_bfloat16;

// 8-byte vector of 4 bf16 for aligned loads/stores
struct __attribute__((aligned(8))) bf16x4 { bf16 x, y, z, w; };

// Mode detect: fp32 inputs -> t[0] is fp32 0.0 -> first 4 bytes == 0.
// bf16 inputs -> bytes are (t0=0x0000, t1=0x3CA4) -> 0x3CA40000 != 0.
__device__ __forceinline__ bool is_fp32_mode(const void* tptr) {
    return ((const unsigned int*)tptr)[0] == 0u;
}

// ---------------------------------------------------------------------------
// 4-element global loads with upcast to fp32
// ---------------------------------------------------------------------------
__device__ __forceinline__ void load4(const float* __restrict__ p, float (&o)[4]) {
    const float4 v = *(const float4*)p;
    o[0] = v.x; o[1] = v.y; o[2] = v.z; o[3] = v.w;
}
__device__ __forceinline__ void load4(const bf16* __restrict__ p, float (&o)[4]) {
    const bf16x4 v = *(const bf16x4*)p;
    o[0] = __bfloat162float(v.x); o[1] = __bfloat162float(v.y);
    o[2] = __bfloat162float(v.z); o[3] = __bfloat162float(v.w);
}

// ---------------------------------------------------------------------------
// Shared fp32 GEMM tile core. A is [M x K] row-major, B is [K x N] row-major.
// Computes this block's 64x64 tile into c[4][4] per thread. LDS is fp32.
// ---------------------------------------------------------------------------
template <int K, int N, typename TA, typename TB>
__device__ __forceinline__ void gemm_tile(const TA* __restrict__ A,
                                          const TB* __restrict__ B,
                                          float (&c)[4][4])
{
    __shared__ float As[BK][BM];   // transposed: As[k][m]
    __shared__ float Bs[BK][BN];   // natural:    Bs[k][n]

    const int tid = threadIdx.x;           // 0..255
    const int tx  = tid & 15;              // 0..15  -> n quad
    const int ty  = tid >> 4;              // 0..15  -> m quad
    const int bm  = blockIdx.y * BM;
    const int bn  = blockIdx.x * BN;

    // A-load mapping: 64 rows x 16 k, 4 elements per thread (k-contiguous)
    const int m_a = tid >> 2;              // 0..63
    const int k_a = (tid & 3) << 2;        // 0,4,8,12
    // B-load mapping: 16 k x 64 n, 4 elements per thread (n-contiguous)
    const int k_b = tid >> 4;              // 0..15
    const int n_b = (tid & 15) << 2;       // 0..60

#pragma unroll
    for (int i = 0; i < 4; ++i)
#pragma unroll
        for (int j = 0; j < 4; ++j) c[i][j] = 0.f;

    for (int k0 = 0; k0 < K; k0 += BK) {
        float av[4], bv[4];
        load4(A + (size_t)(bm + m_a) * K + (k0 + k_a), av);
        load4(B + (size_t)(k0 + k_b) * N + (bn + n_b), bv);
        As[k_a + 0][m_a] = av[0];
        As[k_a + 1][m_a] = av[1];
        As[k_a + 2][m_a] = av[2];
        As[k_a + 3][m_a] = av[3];
        *(float4*)(&Bs[k_b][n_b]) = make_float4(bv[0], bv[1], bv[2], bv[3]);
        __syncthreads();

#pragma unroll
        for (int kk = 0; kk < BK; ++kk) {
            const float4 a = *(const float4*)(&As[kk][ty << 2]);
            const float4 b = *(const float4*)(&Bs[kk][tx << 2]);
            const float ar[4] = {a.x, a.y, a.z, a.w};
            const float br[4] = {b.x, b.y, b.z, b.w};
#pragma unroll
            for (int i = 0; i < 4; ++i)
#pragma unroll
                for (int j = 0; j < 4; ++j) c[i][j] += ar[i] * br[j];
        }
        __syncthreads();
    }
}

// ---------------------------------------------------------------------------
// GEMM1: H = tanh(Z @ W1 + b1)   [1024x512]@[512x1024] -> bf16 [1024x1024]
// Z is fp32 state (zf or zt), W1 is bf16, H stored bf16.
// ---------------------------------------------------------------------------
__global__ __launch_bounds__(256) void gemm1_tanh(const float* __restrict__ Z,
                                                  const bf16* __restrict__ W1b,
                                                  const float* __restrict__ b1f,
                                                  bf16* __restrict__ Hout)
{
    float c[4][4];
    gemm_tile<DLAT, HHID>(Z, W1b, c);

    const int tid = threadIdx.x;
    const int tx  = tid & 15, ty = tid >> 4;
    const int bm  = blockIdx.y * BM;
    const int bn  = blockIdx.x * BN;

    const float4 bb    = *(const float4*)(b1f + bn + (tx << 2));
    const float  b4[4] = {bb.x, bb.y, bb.z, bb.w};

#pragma unroll
    for (int i = 0; i < 4; ++i) {
        const int m = bm + (ty << 2) + i;
        bf16x4 v;
        v.x = __float2bfloat16(tanhf(c[i][0] + b4[0]));
        v.y = __float2bfloat16(tanhf(c[i][1] + b4[1]));
        v.z = __float2bfloat16(tanhf(c[i][2] + b4[2]));
        v.w = __float2bfloat16(tanhf(c[i][3] + b4[3]));
        *(bf16x4*)(Hout + (size_t)m * HHID + bn + (tx << 2)) = v;
    }
}

// ---------------------------------------------------------------------------
// GEMM2 + RK4 stage update:
//   kv = H @ W2 + b2     bf16[1024x1024]@bf16[1024x512] -> fp32 [1024x512]
//   stage 0: acc  = kv;        zt = z + 0.5*dt*kv
//   stage 1: acc += 2kv;       zt = z + 0.5*dt*kv
//   stage 2: acc += 2kv;       zt = z + dt*kv
//   stage 3: z   += dt/6*(acc+kv); traj[step+1] = z (dtype per mode)
// ---------------------------------------------------------------------------
__global__ __launch_bounds__(256) void gemm2_stage(const bf16* __restrict__ Hin,
                                                   const bf16* __restrict__ W2b,
                                                   const float* __restrict__ b2f,
                                                   float* __restrict__ zf,
                                                   float* __restrict__ zt,
                                                   float* __restrict__ acc,
                                                   void* __restrict__ traj,
                                                   const void* __restrict__ tarr,
                                                   int step, int stage)
{
    float c[4][4];
    gemm_tile<HHID, DLAT>(Hin, W2b, c);

    const int tid = threadIdx.x;
    const int tx  = tid & 15, ty = tid >> 4;
    const int bm  = blockIdx.y * BM;
    const int bn  = blockIdx.x * BN;

    const bool fp32m = is_fp32_mode(tarr);
    float tA, tB;
    if (fp32m) {
        const float* tf = (const float*)tarr;
        tA = tf[step]; tB = tf[step + 1];
    } else {
        const bf16* tb = (const bf16*)tarr;
        tA = __bfloat162float(tb[step]); tB = __bfloat162float(tb[step + 1]);
    }
    const float dt = tB - tA;

#pragma unroll
    for (int i = 0; i < 4; ++i) {
        const int m = bm + (ty << 2) + i;
#pragma unroll
        for (int j = 0; j < 4; ++j) {
            const int    n   = bn + (tx << 2) + j;
            const size_t idx = (size_t)m * DLAT + n;
            const float  kv  = c[i][j] + b2f[n];
            if (stage == 0) {
                acc[idx] = kv;
                zt[idx]  = zf[idx] + 0.5f * dt * kv;
            } else if (stage == 1) {
                acc[idx] += 2.f * kv;
                zt[idx]   = zf[idx] + 0.5f * dt * kv;
            } else if (stage == 2) {
                acc[idx] += 2.f * kv;
                zt[idx]   = zf[idx] + dt * kv;
            } else {
                const float zn = zf[idx] + (dt * (1.f / 6.f)) * (acc[idx] + kv);
                zf[idx] = zn;
                const size_t ofs = (size_t)(step + 1) * BD + idx;
                if (fp32m) ((float*)traj)[ofs] = zn;
                else       ((bf16*)traj)[ofs]  = __float2bfloat16(zn);
            }
        }
    }
}

// ---------------------------------------------------------------------------
// Init: normalize inputs into workspace (dtype-adaptive) + traj[0] = z0.
// zf fp32; W1b/W2b bf16 (identity copy in bf16 mode); b1f/b2f fp32.
// ---------------------------------------------------------------------------
__global__ __launch_bounds__(256) void init_kernel(const void* __restrict__ z0,
                                                   const void* __restrict__ tarr,
                                                   const void* __restrict__ W1,
                                                   const void* __restrict__ b1,
                                                   const void* __restrict__ W2,
                                                   const void* __restrict__ b2,
                                                   float* __restrict__ zf,
                                                   bf16* __restrict__ W1b,
                                                   float* __restrict__ b1f,
                                                   bf16* __restrict__ W2b,
                                                   float* __restrict__ b2f,
                                                   void* __restrict__ traj)
{
    const int  idx   = blockIdx.x * blockDim.x + threadIdx.x;
    const bool fp32m = is_fp32_mode(tarr);

    if (idx < BD) {
        if (fp32m) {
            const float zv = ((const float*)z0)[idx];
            zf[idx] = zv;
            ((float*)traj)[idx] = zv;
            W1b[idx] = __float2bfloat16(((const float*)W1)[idx]);
            W2b[idx] = __float2bfloat16(((const float*)W2)[idx]);
        } else {
            const bf16 zv = ((const bf16*)z0)[idx];
            zf[idx] = __bfloat162float(zv);
            ((bf16*)traj)[idx] = zv;
            W1b[idx] = ((const bf16*)W1)[idx];
            W2b[idx] = ((const bf16*)W2)[idx];
        }
    }
    if (idx < HHID)
        b1f[idx] = fp32m ? ((const float*)b1)[idx]
                         : __bfloat162float(((const bf16*)b1)[idx]);
    if (idx < DLAT)
        b2f[idx] = fp32m ? ((const float*)b2)[idx]
                         : __bfloat162float(((const bf16*)b2)[idx]);
}

// ---------------------------------------------------------------------------
extern "C" void kernel_launch(void* const* d_in, const int* in_sizes, int n_in,
                              void* d_out, int out_size, void* d_ws, size_t ws_size,
                              hipStream_t stream)
{
    (void)in_sizes; (void)n_in; (void)out_size; (void)ws_size;

    const void* z0 = d_in[0];
    const void* t  = d_in[1];
    const void* W1 = d_in[2];
    const void* b1 = d_in[3];
    const void* W2 = d_in[4];
    const void* b2 = d_in[5];

    // Workspace carve (~10.0 MiB total):
    //   fp32: zf[BD] zt[BD] acc[BD] b1f[HHID] b2f[DLAT]
    //   bf16: hbuf[BH] W1b[BD] W2b[BD]
    float* ws  = (float*)d_ws;
    float* zf  = ws;                 // BD
    float* zt  = zf  + BD;           // BD
    float* acc = zt  + BD;           // BD
    float* b1f = acc + BD;           // HHID
    float* b2f = b1f + HHID;         // DLAT
    bf16*  hb  = (bf16*)(b2f + DLAT); // BH
    bf16*  W1b = hb  + BH;           // BD
    bf16*  W2b = W1b + BD;           // BD

    init_kernel<<<BD / 256, 256, 0, stream>>>(z0, t, W1, b1, W2, b2,
                                              zf, W1b, b1f, W2b, b2f, d_out);

    const dim3 blk(256);
    const dim3 g1(HHID / BN, BATCH / BM);  // 16 x 16 = 256 blocks
    const dim3 g2(DLAT / BN, BATCH / BM);  //  8 x 16 = 128 blocks

    for (int s = 0; s < TPTS - 1; ++s) {
        for (int stage = 0; stage < 4; ++stage) {
            const float* zin = (stage == 0) ? zf : zt;
            gemm1_tanh<<<g1, blk, 0, stream>>>(zin, W1b, b1f, hb);
            gemm2_stage<<<g2, blk, 0, stream>>>(hb, W2b, b2f, zf, zt, acc,
                                                d_out, t, s, stage);
        }
    }
}

// Round 4
// 18385.878 us; speedup vs baseline: 1.3930x; 1.3930x over previous
//
#include <hip/hip_runtime.h>
#include <hip/hip_bf16.h>

// Problem dims (fixed by reference). All global I/O is fp32.
#define BATCH 1024
#define DLAT  512
#define HHID  1024
#define TPTS  64
#define BD    (BATCH * DLAT)     // 524288

#define MROWS 16                 // batch rows per block
#define NBLK  (BATCH / MROWS)    // 64 persistent blocks
#define NTHR  512                // 8 waves

typedef __attribute__((ext_vector_type(8))) short short8;  // 8 bf16 (4 VGPRs)
typedef __attribute__((ext_vector_type(4))) float f32x4;   // MFMA C/D frag

__device__ __forceinline__ short f2bf(float x) {
    __hip_bfloat16 h = __float2bfloat16(x);
    return __builtin_bit_cast(short, h);
}
__device__ __forceinline__ float fast_tanh(float x) {
    // clamped exp-based tanh: |err| ~1e-7; clamp also kills any NaN/Inf
    x = fminf(9.f, fmaxf(-9.f, x));
    const float e = __expf(2.f * x);
    return (e - 1.f) / (e + 1.f);
}

// mfma_f32_16x16x32_bf16 layouts (m89/m120-verified):
//   A[m = lane&15][k = (lane>>4)*8 + j],  B[k = (lane>>4)*8 + j][n = lane&15]
//   C/D: col = lane&15, row = (lane>>4)*4 + reg
// Fragment-ordered LDS index (in shorts) for A-element (row r, k-col n):
__device__ __forceinline__ int frag_idx(int r, int n) {
    return (((n >> 5) * 64) + (r | (((n >> 3) & 3) << 4))) * 8 + (n & 7);
}

// ---------------------------------------------------------------------------
// init_pack: fp32 W1/W2 -> bf16 MFMA B-fragment order; traj[0] = z0 (fp32).
//   W1p: [K1/32=16][N1/16=64][lane 64][j 8]   (element W1[k][n], k=D, n=H)
//   W2p: [K2/32=32][N2/16=32][lane 64][j 8]   (element W2[k][n], k=H, n=D)
// grid: 256 x 256 = 65536 threads.
// ---------------------------------------------------------------------------
__global__ __launch_bounds__(256) void init_pack(const float* __restrict__ z0,
                                                 const float* __restrict__ W1,
                                                 const float* __restrict__ W2,
                                                 short* __restrict__ W1p,
                                                 short* __restrict__ W2p,
                                                 float* __restrict__ traj)
{
    const int g = blockIdx.x * 256 + threadIdx.x;   // 0..65535

    {   // W1 group: g = ((kt*64 + nt)*64 + l)
        const int kt = g >> 12, rem = g & 4095, nt = rem >> 6, l = rem & 63;
        const int k0 = kt * 32 + (l >> 4) * 8;
        const int n  = nt * 16 + (l & 15);
        short8 v;
#pragma unroll
        for (int j = 0; j < 8; ++j) v[j] = f2bf(W1[(size_t)(k0 + j) * HHID + n]);
        *(short8*)&W1p[(size_t)g * 8] = v;
    }
    {   // W2 group: g = ((kt*32 + nt)*64 + l)
        const int kt = g >> 11, rem = g & 2047, nt = rem >> 6, l = rem & 63;
        const int k0 = kt * 32 + (l >> 4) * 8;
        const int n  = nt * 16 + (l & 15);
        short8 v;
#pragma unroll
        for (int j = 0; j < 8; ++j) v[j] = f2bf(W2[(size_t)(k0 + j) * DLAT + n]);
        *(short8*)&W2p[(size_t)g * 8] = v;
    }
    // traj[0] = z0 exact fp32 copy, 8 floats per thread
    const float4* s = (const float4*)z0;
    float4*       d = (float4*)traj;
    d[(size_t)g * 2 + 0] = s[(size_t)g * 2 + 0];
    d[(size_t)g * 2 + 1] = s[(size_t)g * 2 + 1];
}

// ---------------------------------------------------------------------------
// Persistent ODE kernel: 64 blocks x 16 batch rows, all 63 RK4 steps.
// z state: exact fp32 in registers (ownership = GEMM2 C/D elements).
// A-operands (z, H) are bf16 fragment-order in LDS; weights stream from L2.
// ---------------------------------------------------------------------------
__global__ __launch_bounds__(NTHR) void ode_persistent(
    const float* __restrict__ z0, const float* __restrict__ t,
    const short* __restrict__ W1p, const short* __restrict__ W2p,
    const float* __restrict__ b1, const float* __restrict__ b2,
    float* __restrict__ traj)
{
    __shared__ __align__(16) short Abuf[16 * 64 * 8];   // 16 KB: A (16 x 512)
    __shared__ __align__(16) short HL[32 * 64 * 8];     // 32 KB: H (16 x 1024)
    __shared__ float b1L[HHID];                         //  4 KB
    __shared__ float b2L[DLAT];                         //  2 KB

    const int tid  = threadIdx.x;
    const int lane = tid & 63;
    const int wv   = tid >> 6;       // 0..7
    const int q    = lane >> 4;      // quad
    const int col  = lane & 15;
    const int rb   = blockIdx.x * MROWS;

    for (int i = tid; i < HHID; i += NTHR) b1L[i] = b1[i];
    for (int i = tid; i < DLAT; i += NTHR) b2L[i] = b2[i];

    // Thread ownership (stage-invariant): GEMM2 output elements
    //   tiles tt=0..3 -> n = (wv*4+tt)*16 + col ; regs 0..3 -> r = q*4+reg
    float zreg[4][4];   // exact fp32 integration state
    float kacc[4][4];   // RK4 k-accumulator

#pragma unroll
    for (int tt = 0; tt < 4; ++tt) {
        const int n = (wv * 4 + tt) * 16 + col;
#pragma unroll
        for (int reg = 0; reg < 4; ++reg) {
            const int r  = q * 4 + reg;
            const float zv = z0[(size_t)(rb + r) * DLAT + n];
            zreg[tt][reg] = zv;
            Abuf[frag_idx(r, n)] = f2bf(zv);
        }
    }
    __syncthreads();

    for (int step = 0; step < TPTS - 1; ++step) {
        const float dt = t[step + 1] - t[step];

        for (int stage = 0; stage < 4; ++stage) {
            // ================= GEMM1: H = tanh(A @ W1 + b1) =================
            // wave owns col-tiles nt = wv*8 .. wv*8+7 (N=1024)
            {
                f32x4 hacc[8];
#pragma unroll
                for (int c = 0; c < 8; ++c) hacc[c] = (f32x4){0.f, 0.f, 0.f, 0.f};

                short8 a0 = *(const short8*)&Abuf[lane * 8];
                short8 b0[8];
                {
                    const short* bp = W1p + ((size_t)(wv * 8) * 64 + lane) * 8;
#pragma unroll
                    for (int c = 0; c < 8; ++c) b0[c] = *(const short8*)(bp + c * 512);
                }
#pragma unroll
                for (int kt = 0; kt < 16; ++kt) {
                    const int ktn = (kt < 15) ? kt + 1 : 15;   // clamped prefetch
                    short8 a1 = *(const short8*)&Abuf[(ktn * 64 + lane) * 8];
                    short8 b1v[8];
                    const short* bp =
                        W1p + (((size_t)ktn * 64 + wv * 8) * 64 + lane) * 8;
#pragma unroll
                    for (int c = 0; c < 8; ++c)
                        b1v[c] = *(const short8*)(bp + c * 512);
#pragma unroll
                    for (int c = 0; c < 8; ++c)
                        hacc[c] = __builtin_amdgcn_mfma_f32_16x16x32_bf16(
                            a0, b0[c], hacc[c], 0, 0, 0);
                    a0 = a1;
#pragma unroll
                    for (int c = 0; c < 8; ++c) b0[c] = b1v[c];
                }
                // epilogue: bias + tanh -> HL in GEMM2-A fragment order
#pragma unroll
                for (int c = 0; c < 8; ++c) {
                    const int Hc   = (wv * 8 + c) * 16 + col;
                    const float bb = b1L[Hc];
#pragma unroll
                    for (int reg = 0; reg < 4; ++reg) {
                        const int r = q * 4 + reg;
                        HL[frag_idx(r, Hc)] = f2bf(fast_tanh(hacc[c][reg] + bb));
                    }
                }
            }
            __syncthreads();

            // ============ GEMM2: kv = H @ W2 + b2 ; RK4 stage update =========
            // wave owns col-tiles nt2 = wv*4 .. wv*4+3 (N=512)
            {
                f32x4 kv4[4];
#pragma unroll
                for (int c = 0; c < 4; ++c) kv4[c] = (f32x4){0.f, 0.f, 0.f, 0.f};

                short8 a0 = *(const short8*)&HL[lane * 8];
                short8 b0[4];
                {
                    const short* bp = W2p + ((size_t)(wv * 4) * 64 + lane) * 8;
#pragma unroll
                    for (int c = 0; c < 4; ++c) b0[c] = *(const short8*)(bp + c * 512);
                }
#pragma unroll
                for (int kt = 0; kt < 32; ++kt) {
                    const int ktn = (kt < 31) ? kt + 1 : 31;   // clamped prefetch
                    short8 a1 = *(const short8*)&HL[(ktn * 64 + lane) * 8];
                    short8 b1v[4];
                    const short* bp =
                        W2p + (((size_t)ktn * 32 + wv * 4) * 64 + lane) * 8;
#pragma unroll
                    for (int c = 0; c < 4; ++c)
                        b1v[c] = *(const short8*)(bp + c * 512);
#pragma unroll
                    for (int c = 0; c < 4; ++c)
                        kv4[c] = __builtin_amdgcn_mfma_f32_16x16x32_bf16(
                            a0, b0[c], kv4[c], 0, 0, 0);
                    a0 = a1;
#pragma unroll
                    for (int c = 0; c < 4; ++c) b0[c] = b1v[c];
                }
                // epilogue: RK4 stage update (registers) + next A into Abuf
#pragma unroll
                for (int tt = 0; tt < 4; ++tt) {
                    const int n    = (wv * 4 + tt) * 16 + col;
                    const float bb = b2L[n];
#pragma unroll
                    for (int reg = 0; reg < 4; ++reg) {
                        const int r  = q * 4 + reg;
                        const float kv = kv4[tt][reg] + bb;
                        float znext;
                        if (stage == 0) {
                            kacc[tt][reg] = kv;
                            znext = zreg[tt][reg] + 0.5f * dt * kv;
                        } else if (stage == 1) {
                            kacc[tt][reg] += 2.f * kv;
                            znext = zreg[tt][reg] + 0.5f * dt * kv;
                        } else if (stage == 2) {
                            kacc[tt][reg] += 2.f * kv;
                            znext = zreg[tt][reg] + dt * kv;
                        } else {
                            zreg[tt][reg] += (dt * (1.f / 6.f)) * (kacc[tt][reg] + kv);
                            znext = zreg[tt][reg];
                        }
                        Abuf[frag_idx(r, n)] = f2bf(znext);
                    }
                }
            }
            __syncthreads();
        }

        // traj[step+1] = exact fp32 z straight from registers (no sync needed)
#pragma unroll
        for (int tt = 0; tt < 4; ++tt) {
            const int n = (wv * 4 + tt) * 16 + col;
#pragma unroll
            for (int reg = 0; reg < 4; ++reg) {
                const int r = q * 4 + reg;
                traj[(size_t)(step + 1) * BD + (size_t)(rb + r) * DLAT + n] =
                    zreg[tt][reg];
            }
        }
    }
}

// ---------------------------------------------------------------------------
extern "C" void kernel_launch(void* const* d_in, const int* in_sizes, int n_in,
                              void* d_out, int out_size, void* d_ws, size_t ws_size,
                              hipStream_t stream)
{
    (void)in_sizes; (void)n_in; (void)out_size; (void)ws_size;

    const float* z0 = (const float*)d_in[0];
    const float* t  = (const float*)d_in[1];
    const float* W1 = (const float*)d_in[2];
    const float* b1 = (const float*)d_in[3];
    const float* W2 = (const float*)d_in[4];
    const float* b2 = (const float*)d_in[5];
    float*       traj = (float*)d_out;

    // Workspace: packed bf16 weights, 1 MB each
    short* W1p = (short*)d_ws;           // 512K shorts
    short* W2p = W1p + (size_t)BD;       // 512K shorts

    init_pack<<<256, 256, 0, stream>>>(z0, W1, W2, W1p, W2p, traj);
    ode_persistent<<<NBLK, NTHR, 0, stream>>>(z0, t, W1p, W2p, b1, b2, traj);
}